// Round 1
// baseline (459.720 us; speedup 1.0000x reference)
//
#include <hip/hip_runtime.h>
#include <hip/hip_bf16.h>
#include <cstdint>

#define QEPS 1e-6f

typedef int v4i __attribute__((ext_vector_type(4)));

__device__ __forceinline__ void gl_lds16(const void* g, void* l) {
  __builtin_amdgcn_global_load_lds(
      (const __attribute__((address_space(1))) void*)g,
      (__attribute__((address_space(3))) void*)l, 16, 0, 0);
}

// ---------------- Kernel 1: weight quantization ----------------
// One block per output row n. w_scales[n] = max(|w[n,:]|, EPS)/7; qw = clip(round(w/scale),-8,7)
__global__ __launch_bounds__(256) void wquant_kernel(const float* __restrict__ w,
                                                     int8_t* __restrict__ qw,
                                                     float* __restrict__ wscale) {
  const int n = blockIdx.x;
  const int t = threadIdx.x;
  const float4* wrow = (const float4*)(w + (size_t)n * 4096);
  float4 v[4];
  float am = 0.f;
#pragma unroll
  for (int i = 0; i < 4; ++i) {
    v[i] = wrow[i * 256 + t];
    am = fmaxf(am, fmaxf(fmaxf(fabsf(v[i].x), fabsf(v[i].y)),
                         fmaxf(fabsf(v[i].z), fabsf(v[i].w))));
  }
#pragma unroll
  for (int off = 32; off > 0; off >>= 1)
    am = fmaxf(am, __shfl_down(am, off));
  __shared__ float wm[4];
  if ((t & 63) == 0) wm[t >> 6] = am;
  __syncthreads();
  const float rowmax = fmaxf(fmaxf(wm[0], wm[1]), fmaxf(wm[2], wm[3]));
  const float scale = fmaxf(rowmax, QEPS) / 7.0f;  // matches ref: clip(...)/7.0
  if (t == 0) wscale[n] = scale;
  char4* qrow = (char4*)(qw + (size_t)n * 4096);
#pragma unroll
  for (int i = 0; i < 4; ++i) {
    char4 q;
    q.x = (signed char)fminf(fmaxf(rintf(v[i].x / scale), -8.f), 7.f);
    q.y = (signed char)fminf(fmaxf(rintf(v[i].y / scale), -8.f), 7.f);
    q.z = (signed char)fminf(fmaxf(rintf(v[i].z / scale), -8.f), 7.f);
    q.w = (signed char)fminf(fmaxf(rintf(v[i].w / scale), -8.f), 7.f);
    qrow[i * 256 + t] = q;
  }
}

// ---------------- Kernel 2: FWHT + activation quantization ----------------
// One block per row m. In-LDS FWHT (identical butterfly tree to reference),
// x2 = fwht(x)/64; sx = max(max|x2|,EPS)*(1/7); qx = clip(round(x2/sx),-8,7)
__global__ __launch_bounds__(256) void xquant_kernel(const float* __restrict__ x,
                                                     int8_t* __restrict__ qx,
                                                     float* __restrict__ sx) {
  const int m = blockIdx.x;
  const int t = threadIdx.x;
  __shared__ float s[4096];
  float4* sv = (float4*)s;
  const float4* xrow = (const float4*)(x + (size_t)m * 4096);
#pragma unroll
  for (int i = 0; i < 4; ++i) sv[i * 256 + t] = xrow[i * 256 + t];
  for (int h = 1; h < 4096; h <<= 1) {
    __syncthreads();
#pragma unroll
    for (int j = 0; j < 8; ++j) {
      const int p = j * 256 + t;
      const int i0 = ((p & ~(h - 1)) << 1) | (p & (h - 1));
      const float a = s[i0];
      const float b = s[i0 + h];
      s[i0] = a + b;
      s[i0 + h] = a - b;
    }
  }
  __syncthreads();
  float4 v[4];
  float am = 0.f;
#pragma unroll
  for (int i = 0; i < 4; ++i) {
    v[i] = sv[i * 256 + t];
    am = fmaxf(am, fmaxf(fmaxf(fabsf(v[i].x), fabsf(v[i].y)),
                         fmaxf(fabsf(v[i].z), fabsf(v[i].w))));
  }
#pragma unroll
  for (int off = 32; off > 0; off >>= 1)
    am = fmaxf(am, __shfl_down(am, off));
  __shared__ float wm[4];
  if ((t & 63) == 0) wm[t >> 6] = am;
  __syncthreads();
  const float rowmax = fmaxf(fmaxf(wm[0], wm[1]), fmaxf(wm[2], wm[3]));
  // x2 = raw/64 (exact pow2 scale commutes with max)
  const float sxv = fmaxf(rowmax * (1.0f / 64.0f), QEPS) * (float)(1.0 / 7.0);
  if (t == 0) sx[m] = sxv;
  char4* qrow = (char4*)(qx + (size_t)m * 4096);
#pragma unroll
  for (int i = 0; i < 4; ++i) {
    char4 q;
    q.x = (signed char)fminf(fmaxf(rintf((v[i].x * (1.0f / 64.0f)) / sxv), -8.f), 7.f);
    q.y = (signed char)fminf(fmaxf(rintf((v[i].y * (1.0f / 64.0f)) / sxv), -8.f), 7.f);
    q.z = (signed char)fminf(fmaxf(rintf((v[i].z * (1.0f / 64.0f)) / sxv), -8.f), 7.f);
    q.w = (signed char)fminf(fmaxf(rintf((v[i].w * (1.0f / 64.0f)) / sxv), -8.f), 7.f);
    qrow[i * 256 + t] = q;
  }
}

// ---------------- Kernel 3: int8 GEMM (qx * qw^T) + epilogue ----------------
// 128x128 tile per 256-thread block, BK=64, mfma_i32_16x16x64_i8.
// Wave (2x2) owns a 64x64 sub-tile = 4x4 grid of 16x16 MFMA tiles.
#define BM 128
#define BN 128
#define BK 64

__global__ __launch_bounds__(256) void gemm_kernel(const int8_t* __restrict__ qx,
                                                   const int8_t* __restrict__ qw,
                                                   const float* __restrict__ sx,
                                                   const float* __restrict__ wscale,
                                                   const float* __restrict__ bias,
                                                   float* __restrict__ out) {
  __shared__ int8_t As[BM * BK] __attribute__((aligned(16)));
  __shared__ int8_t Bs[BN * BK] __attribute__((aligned(16)));
  const int t = threadIdx.x;
  const int m0 = blockIdx.y * BM;
  const int n0 = blockIdx.x * BN;
  const int lane = t & 63;
  const int wave = t >> 6;
  const int wr = wave >> 1;  // wave row 0..1 (m)
  const int wc = wave & 1;   // wave col 0..1 (n)
  const int lr = lane & 15;
  const int lq = lane >> 4;

  v4i acc[4][4] = {};

  // staging: 8192 B per tile = 256 threads * 2 chunks * 16 B
  const int flat0 = t * 16;       // 0..4080
  const int row0 = flat0 >> 6;    // 0..63
  const int col0 = flat0 & 63;
  const int8_t* gA0 = qx + (size_t)(m0 + row0) * 4096 + col0;
  const int8_t* gA1 = qx + (size_t)(m0 + 64 + row0) * 4096 + col0;
  const int8_t* gB0 = qw + (size_t)(n0 + row0) * 4096 + col0;
  const int8_t* gB1 = qw + (size_t)(n0 + 64 + row0) * 4096 + col0;

  for (int k0 = 0; k0 < 4096; k0 += BK) {
    __syncthreads();
    gl_lds16(gA0 + k0, As + flat0);
    gl_lds16(gA1 + k0, As + 4096 + flat0);
    gl_lds16(gB0 + k0, Bs + flat0);
    gl_lds16(gB1 + k0, Bs + 4096 + flat0);
    __syncthreads();

    v4i a[4], b[4];
#pragma unroll
    for (int mt = 0; mt < 4; ++mt)
      a[mt] = *(const v4i*)(As + (wr * 64 + mt * 16 + lr) * 64 + lq * 16);
#pragma unroll
    for (int nt = 0; nt < 4; ++nt)
      b[nt] = *(const v4i*)(Bs + (wc * 64 + nt * 16 + lr) * 64 + lq * 16);
#pragma unroll
    for (int mt = 0; mt < 4; ++mt)
#pragma unroll
      for (int nt = 0; nt < 4; ++nt)
        acc[mt][nt] = __builtin_amdgcn_mfma_i32_16x16x64_i8(a[mt], b[nt], acc[mt][nt], 0, 0, 0);
  }

  // epilogue: y = qy * sx[m] * ws[n] + bias[n]
  // C/D layout: n(col)=lane&15, m(row)=(lane>>4)*4+reg
#pragma unroll
  for (int mt = 0; mt < 4; ++mt) {
#pragma unroll
    for (int r = 0; r < 4; ++r) {
      const int m = m0 + wr * 64 + mt * 16 + lq * 4 + r;
      const float sm = sx[m];
#pragma unroll
      for (int nt = 0; nt < 4; ++nt) {
        const int n = n0 + wc * 64 + nt * 16 + lr;
        out[(size_t)m * 4096 + n] = (float)acc[mt][nt][r] * sm * wscale[n] + bias[n];
      }
    }
  }
}

extern "C" void kernel_launch(void* const* d_in, const int* in_sizes, int n_in,
                              void* d_out, int out_size, void* d_ws, size_t ws_size,
                              hipStream_t stream) {
  const float* x = (const float*)d_in[0];       // 8192 x 4096
  const float* w = (const float*)d_in[1];       // 4096 x 4096
  const float* bias = (const float*)d_in[2];    // 4096
  float* out = (float*)d_out;                   // 8192 x 4096

  int8_t* qx = (int8_t*)d_ws;                                  // 32 MiB
  int8_t* qw = qx + (size_t)8192 * 4096;                       // 16 MiB
  float* wscale = (float*)(qw + (size_t)4096 * 4096);          // 16 KiB
  float* sxp = wscale + 4096;                                  // 32 KiB

  wquant_kernel<<<4096, 256, 0, stream>>>(w, qw, wscale);
  xquant_kernel<<<8192, 256, 0, stream>>>(x, qx, sxp);
  dim3 grid(4096 / BN, 8192 / BM);
  gemm_kernel<<<grid, 256, 0, stream>>>(qx, qw, sxp, wscale, bias, out);
}

// Round 2
// 438.608 us; speedup vs baseline: 1.0481x; 1.0481x over previous
//
#include <hip/hip_runtime.h>
#include <hip/hip_bf16.h>
#include <cstdint>

#define QEPS 1e-6f

typedef int v4i __attribute__((ext_vector_type(4)));

__device__ __forceinline__ void gl_lds16(const void* g, void* l) {
  __builtin_amdgcn_global_load_lds(
      (const __attribute__((address_space(1))) void*)g,
      (__attribute__((address_space(3))) void*)l, 16, 0, 0);
}

// ---------------- Kernel 1: weight quantization ----------------
__global__ __launch_bounds__(256) void wquant_kernel(const float* __restrict__ w,
                                                     int8_t* __restrict__ qw,
                                                     float* __restrict__ wscale) {
  const int n = blockIdx.x;
  const int t = threadIdx.x;
  const float4* wrow = (const float4*)(w + (size_t)n * 4096);
  float4 v[4];
  float am = 0.f;
#pragma unroll
  for (int i = 0; i < 4; ++i) {
    v[i] = wrow[i * 256 + t];
    am = fmaxf(am, fmaxf(fmaxf(fabsf(v[i].x), fabsf(v[i].y)),
                         fmaxf(fabsf(v[i].z), fabsf(v[i].w))));
  }
#pragma unroll
  for (int off = 32; off > 0; off >>= 1)
    am = fmaxf(am, __shfl_down(am, off));
  __shared__ float wm[4];
  if ((t & 63) == 0) wm[t >> 6] = am;
  __syncthreads();
  const float rowmax = fmaxf(fmaxf(wm[0], wm[1]), fmaxf(wm[2], wm[3]));
  const float scale = fmaxf(rowmax, QEPS) / 7.0f;
  if (t == 0) wscale[n] = scale;
  char4* qrow = (char4*)(qw + (size_t)n * 4096);
#pragma unroll
  for (int i = 0; i < 4; ++i) {
    char4 q;
    q.x = (signed char)fminf(fmaxf(rintf(v[i].x / scale), -8.f), 7.f);
    q.y = (signed char)fminf(fmaxf(rintf(v[i].y / scale), -8.f), 7.f);
    q.z = (signed char)fminf(fmaxf(rintf(v[i].z / scale), -8.f), 7.f);
    q.w = (signed char)fminf(fmaxf(rintf(v[i].w / scale), -8.f), 7.f);
    qrow[i * 256 + t] = q;
  }
}

// ---------------- Kernel 2: FWHT + activation quantization ----------------
// One WAVE per row; 64 floats/lane in registers. Element index
// i = j*256 + lane*4 + c  (j = float4 reg 0..15, c = component).
// Stage order identical to reference: h=1,2 (c bits, reg), h=4..128 (lane
// bits, shfl_xor), h=256..2048 (j bits, reg). Bit-identical fp32 tree.
__global__ __launch_bounds__(256) void xquant_kernel(const float* __restrict__ x,
                                                     int8_t* __restrict__ qx,
                                                     float* __restrict__ sx) {
  const int m = blockIdx.x * 4 + (threadIdx.x >> 6);
  const int g = threadIdx.x & 63;
  const float4* xrow = (const float4*)(x + (size_t)m * 4096);
  float4 v[16];
#pragma unroll
  for (int j = 0; j < 16; ++j) v[j] = xrow[j * 64 + g];

  // h = 1
#pragma unroll
  for (int j = 0; j < 16; ++j) {
    float a0 = v[j].x, b0 = v[j].y, a1 = v[j].z, b1 = v[j].w;
    v[j].x = a0 + b0; v[j].y = a0 - b0;
    v[j].z = a1 + b1; v[j].w = a1 - b1;
  }
  // h = 2
#pragma unroll
  for (int j = 0; j < 16; ++j) {
    float a0 = v[j].x, b0 = v[j].z, a1 = v[j].y, b1 = v[j].w;
    v[j].x = a0 + b0; v[j].z = a0 - b0;
    v[j].y = a1 + b1; v[j].w = a1 - b1;
  }
  // h = 4..128 : cross-lane, partner = g ^ (h>>2)
#pragma unroll
  for (int d = 1; d < 64; d <<= 1) {
    const bool low = (g & d) == 0;
#pragma unroll
    for (int j = 0; j < 16; ++j) {
      float px = __shfl_xor(v[j].x, d);
      float py = __shfl_xor(v[j].y, d);
      float pz = __shfl_xor(v[j].z, d);
      float pw = __shfl_xor(v[j].w, d);
      v[j].x = low ? (v[j].x + px) : (px - v[j].x);
      v[j].y = low ? (v[j].y + py) : (py - v[j].y);
      v[j].z = low ? (v[j].z + pz) : (pz - v[j].z);
      v[j].w = low ? (v[j].w + pw) : (pw - v[j].w);
    }
  }
  // h = 256..2048 : register pairs (j, j+d)
#pragma unroll
  for (int d = 1; d < 16; d <<= 1) {
#pragma unroll
    for (int j = 0; j < 16; ++j) {
      if ((j & d) == 0) {
        float4 a = v[j], b = v[j + d];
        v[j].x = a.x + b.x; v[j].y = a.y + b.y;
        v[j].z = a.z + b.z; v[j].w = a.w + b.w;
        v[j + d].x = a.x - b.x; v[j + d].y = a.y - b.y;
        v[j + d].z = a.z - b.z; v[j + d].w = a.w - b.w;
      }
    }
  }

  float am = 0.f;
#pragma unroll
  for (int j = 0; j < 16; ++j)
    am = fmaxf(am, fmaxf(fmaxf(fabsf(v[j].x), fabsf(v[j].y)),
                         fmaxf(fabsf(v[j].z), fabsf(v[j].w))));
#pragma unroll
  for (int off = 32; off > 0; off >>= 1)
    am = fmaxf(am, __shfl_xor(am, off));

  const float inv64 = 1.0f / 64.0f;
  const float sxv = fmaxf(am * inv64, QEPS) * (1.0f / 7.0f);
  if (g == 0) sx[m] = sxv;

  char4* qrow = (char4*)(qx + (size_t)m * 4096);
#pragma unroll
  for (int j = 0; j < 16; ++j) {
    char4 q;
    q.x = (signed char)fminf(fmaxf(rintf((v[j].x * inv64) / sxv), -8.f), 7.f);
    q.y = (signed char)fminf(fmaxf(rintf((v[j].y * inv64) / sxv), -8.f), 7.f);
    q.z = (signed char)fminf(fmaxf(rintf((v[j].z * inv64) / sxv), -8.f), 7.f);
    q.w = (signed char)fminf(fmaxf(rintf((v[j].w * inv64) / sxv), -8.f), 7.f);
    qrow[j * 64 + g] = q;
  }
}

// ---------------- Kernel 3: int8 GEMM (qx * qw^T) + epilogue ----------------
// 128x128 tile, BK=64, mfma_i32_16x16x64_i8, XOR-swizzled LDS to kill the
// 4-way bank conflict on ds_read_b128 fragment loads.
// LDS layout: slot(row, c) = row*64 + (c ^ ((row>>1)&3))*16.
// Swizzle applied at the GLOBAL source address (chunk permute within the
// 64B cache line) so global_load_lds's contiguous LDS write is preserved.
#define BM 128
#define BN 128
#define BK 64

__global__ __launch_bounds__(256) void gemm_kernel(const int8_t* __restrict__ qx,
                                                   const int8_t* __restrict__ qw,
                                                   const float* __restrict__ sx,
                                                   const float* __restrict__ wscale,
                                                   const float* __restrict__ bias,
                                                   float* __restrict__ out) {
  __shared__ int8_t As[BM * BK] __attribute__((aligned(16)));
  __shared__ int8_t Bs[BN * BK] __attribute__((aligned(16)));
  const int t = threadIdx.x;
  const int m0 = blockIdx.y * BM;
  const int n0 = blockIdx.x * BN;
  const int lane = t & 63;
  const int wave = t >> 6;
  const int wr = wave >> 1;
  const int wc = wave & 1;
  const int lr = lane & 15;
  const int lq = lane >> 4;

  v4i acc[4][4] = {};

  // staging: LDS slot = t*16 (contiguous); global chunk = slot-chunk ^ swizzle(row)
  const int flat0 = t * 16;
  const int row0 = flat0 >> 6;                 // 0..63
  const int c_src = (t & 3) ^ ((t >> 3) & 3);  // (c_slot) ^ ((row0>>1)&3)
  const int goff = row0 * 4096 + c_src * 16;
  const int8_t* gA0 = qx + (size_t)m0 * 4096 + goff;
  const int8_t* gA1 = qx + (size_t)(m0 + 64) * 4096 + goff;
  const int8_t* gB0 = qw + (size_t)n0 * 4096 + goff;
  const int8_t* gB1 = qw + (size_t)(n0 + 64) * 4096 + goff;

  // fragment LDS offsets (k-invariant): swizzle = (lr>>1)&3
  const int swz = (lr >> 1) & 3;
  int aoff[4], boff[4];
#pragma unroll
  for (int i = 0; i < 4; ++i) {
    aoff[i] = (wr * 64 + i * 16 + lr) * 64 + ((lq ^ swz) * 16);
    boff[i] = (wc * 64 + i * 16 + lr) * 64 + ((lq ^ swz) * 16);
  }

  for (int k0 = 0; k0 < 4096; k0 += BK) {
    __syncthreads();
    gl_lds16(gA0 + k0, As + flat0);
    gl_lds16(gA1 + k0, As + 4096 + flat0);
    gl_lds16(gB0 + k0, Bs + flat0);
    gl_lds16(gB1 + k0, Bs + 4096 + flat0);
    __syncthreads();

    v4i a[4], b[4];
#pragma unroll
    for (int mt = 0; mt < 4; ++mt) a[mt] = *(const v4i*)(As + aoff[mt]);
#pragma unroll
    for (int nt = 0; nt < 4; ++nt) b[nt] = *(const v4i*)(Bs + boff[nt]);
#pragma unroll
    for (int mt = 0; mt < 4; ++mt)
#pragma unroll
      for (int nt = 0; nt < 4; ++nt)
        acc[mt][nt] = __builtin_amdgcn_mfma_i32_16x16x64_i8(a[mt], b[nt], acc[mt][nt], 0, 0, 0);
  }

  // epilogue: y = qy * sx[m] * ws[n] + bias[n]; C/D: col=lane&15, row=(lane>>4)*4+reg
#pragma unroll
  for (int mt = 0; mt < 4; ++mt) {
#pragma unroll
    for (int r = 0; r < 4; ++r) {
      const int m = m0 + wr * 64 + mt * 16 + lq * 4 + r;
      const float sm = sx[m];
#pragma unroll
      for (int nt = 0; nt < 4; ++nt) {
        const int n = n0 + wc * 64 + nt * 16 + lr;
        out[(size_t)m * 4096 + n] = (float)acc[mt][nt][r] * sm * wscale[n] + bias[n];
      }
    }
  }
}

extern "C" void kernel_launch(void* const* d_in, const int* in_sizes, int n_in,
                              void* d_out, int out_size, void* d_ws, size_t ws_size,
                              hipStream_t stream) {
  const float* x = (const float*)d_in[0];
  const float* w = (const float*)d_in[1];
  const float* bias = (const float*)d_in[2];
  float* out = (float*)d_out;

  int8_t* qx = (int8_t*)d_ws;
  int8_t* qw = qx + (size_t)8192 * 4096;
  float* wscale = (float*)(qw + (size_t)4096 * 4096);
  float* sxp = wscale + 4096;

  wquant_kernel<<<4096, 256, 0, stream>>>(w, qw, wscale);
  xquant_kernel<<<2048, 256, 0, stream>>>(x, qx, sxp);
  dim3 grid(4096 / BN, 8192 / BM);
  gemm_kernel<<<grid, 256, 0, stream>>>(qx, qw, sxp, wscale, bias, out);
}

// Round 3
// 417.550 us; speedup vs baseline: 1.1010x; 1.0504x over previous
//
#include <hip/hip_runtime.h>
#include <hip/hip_bf16.h>
#include <cstdint>

#define QEPS 1e-6f

typedef int v4i __attribute__((ext_vector_type(4)));
typedef int v8i __attribute__((ext_vector_type(8)));
typedef float v4f __attribute__((ext_vector_type(4)));

__device__ __forceinline__ void gl_lds16(const void* g, void* l) {
  __builtin_amdgcn_global_load_lds(
      (const __attribute__((address_space(1))) void*)g,
      (__attribute__((address_space(3))) void*)l, 16, 0, 0);
}

// Encode integer q in [-8,7] (as float) to OCP fp8 e4m3 byte, exact.
__device__ __forceinline__ uint8_t enc_e4m3(float q) {
  const int idx = (int)q + 8;  // 0..15
  const unsigned long long lo = 0xB8C0C4C8CACCCED0ull;  // q=-8..-1 (LSB first)
  const unsigned long long hi = 0x4E4C4A4844403800ull;  // q= 0..7
  const unsigned long long tbl = (idx < 8) ? lo : hi;
  return (uint8_t)(tbl >> ((idx & 7) * 8));
}

// ---------------- Kernel 1: weight quantization -> fp8 e4m3 ----------------
__global__ __launch_bounds__(256) void wquant_kernel(const float* __restrict__ w,
                                                     uint8_t* __restrict__ qw,
                                                     float* __restrict__ wscale) {
  const int n = blockIdx.x;
  const int t = threadIdx.x;
  const float4* wrow = (const float4*)(w + (size_t)n * 4096);
  float4 v[4];
  float am = 0.f;
#pragma unroll
  for (int i = 0; i < 4; ++i) {
    v[i] = wrow[i * 256 + t];
    am = fmaxf(am, fmaxf(fmaxf(fabsf(v[i].x), fabsf(v[i].y)),
                         fmaxf(fabsf(v[i].z), fabsf(v[i].w))));
  }
#pragma unroll
  for (int off = 32; off > 0; off >>= 1)
    am = fmaxf(am, __shfl_down(am, off));
  __shared__ float wm[4];
  if ((t & 63) == 0) wm[t >> 6] = am;
  __syncthreads();
  const float rowmax = fmaxf(fmaxf(wm[0], wm[1]), fmaxf(wm[2], wm[3]));
  const float scale = fmaxf(rowmax, QEPS) / 7.0f;
  if (t == 0) wscale[n] = scale;
  uchar4* qrow = (uchar4*)(qw + (size_t)n * 4096);
#pragma unroll
  for (int i = 0; i < 4; ++i) {
    uchar4 q;
    q.x = enc_e4m3(fminf(fmaxf(rintf(v[i].x / scale), -8.f), 7.f));
    q.y = enc_e4m3(fminf(fmaxf(rintf(v[i].y / scale), -8.f), 7.f));
    q.z = enc_e4m3(fminf(fmaxf(rintf(v[i].z / scale), -8.f), 7.f));
    q.w = enc_e4m3(fminf(fmaxf(rintf(v[i].w / scale), -8.f), 7.f));
    qrow[i * 256 + t] = q;
  }
}

// ---------------- Kernel 2: FWHT + activation quantization -> fp8 ----------------
// One WAVE per row; identical butterfly tree to the reference (bit-identical fp32).
__global__ __launch_bounds__(256) void xquant_kernel(const float* __restrict__ x,
                                                     uint8_t* __restrict__ qx,
                                                     float* __restrict__ sx) {
  const int m = blockIdx.x * 4 + (threadIdx.x >> 6);
  const int g = threadIdx.x & 63;
  const float4* xrow = (const float4*)(x + (size_t)m * 4096);
  float4 v[16];
#pragma unroll
  for (int j = 0; j < 16; ++j) v[j] = xrow[j * 64 + g];

  // h = 1
#pragma unroll
  for (int j = 0; j < 16; ++j) {
    float a0 = v[j].x, b0 = v[j].y, a1 = v[j].z, b1 = v[j].w;
    v[j].x = a0 + b0; v[j].y = a0 - b0;
    v[j].z = a1 + b1; v[j].w = a1 - b1;
  }
  // h = 2
#pragma unroll
  for (int j = 0; j < 16; ++j) {
    float a0 = v[j].x, b0 = v[j].z, a1 = v[j].y, b1 = v[j].w;
    v[j].x = a0 + b0; v[j].z = a0 - b0;
    v[j].y = a1 + b1; v[j].w = a1 - b1;
  }
  // h = 4..128 : cross-lane
#pragma unroll
  for (int d = 1; d < 64; d <<= 1) {
    const bool low = (g & d) == 0;
#pragma unroll
    for (int j = 0; j < 16; ++j) {
      float px = __shfl_xor(v[j].x, d);
      float py = __shfl_xor(v[j].y, d);
      float pz = __shfl_xor(v[j].z, d);
      float pw = __shfl_xor(v[j].w, d);
      v[j].x = low ? (v[j].x + px) : (px - v[j].x);
      v[j].y = low ? (v[j].y + py) : (py - v[j].y);
      v[j].z = low ? (v[j].z + pz) : (pz - v[j].z);
      v[j].w = low ? (v[j].w + pw) : (pw - v[j].w);
    }
  }
  // h = 256..2048 : register pairs
#pragma unroll
  for (int d = 1; d < 16; d <<= 1) {
#pragma unroll
    for (int j = 0; j < 16; ++j) {
      if ((j & d) == 0) {
        float4 a = v[j], b = v[j + d];
        v[j].x = a.x + b.x; v[j].y = a.y + b.y;
        v[j].z = a.z + b.z; v[j].w = a.w + b.w;
        v[j + d].x = a.x - b.x; v[j + d].y = a.y - b.y;
        v[j + d].z = a.z - b.z; v[j + d].w = a.w - b.w;
      }
    }
  }

  float am = 0.f;
#pragma unroll
  for (int j = 0; j < 16; ++j)
    am = fmaxf(am, fmaxf(fmaxf(fabsf(v[j].x), fabsf(v[j].y)),
                         fmaxf(fabsf(v[j].z), fabsf(v[j].w))));
#pragma unroll
  for (int off = 32; off > 0; off >>= 1)
    am = fmaxf(am, __shfl_xor(am, off));

  const float inv64 = 1.0f / 64.0f;
  const float sxv = fmaxf(am * inv64, QEPS) * (1.0f / 7.0f);
  if (g == 0) sx[m] = sxv;

  uchar4* qrow = (uchar4*)(qx + (size_t)m * 4096);
#pragma unroll
  for (int j = 0; j < 16; ++j) {
    uchar4 q;
    q.x = enc_e4m3(fminf(fmaxf(rintf((v[j].x * inv64) / sxv), -8.f), 7.f));
    q.y = enc_e4m3(fminf(fmaxf(rintf((v[j].y * inv64) / sxv), -8.f), 7.f));
    q.z = enc_e4m3(fminf(fmaxf(rintf((v[j].z * inv64) / sxv), -8.f), 7.f));
    q.w = enc_e4m3(fminf(fmaxf(rintf((v[j].w * inv64) / sxv), -8.f), 7.f));
    qrow[j * 64 + g] = q;
  }
}

// ---------------- Kernel 3: MX-fp8 GEMM (qx * qw^T) + epilogue ----------------
// 128x128 tile, BK=128, mfma_scale_f32_16x16x128_f8f6f4 with identity scales.
// LDS row = 128 B = 8 chunks of 16 B; chunk stored at position c ^ (row&7)
// (swizzle applied at the global source so global_load_lds stays contiguous).
// Fragment (lane lr,lq): bytes lq*32..lq*32+31 of its row = logical chunks
// 2lq, 2lq+1 -> stored at (2lq)^(lr&7), (2lq+1)^(lr&7): even 8-lane/quad spread.
#define BM 128
#define BN 128
#define BK 128

__global__ __launch_bounds__(256) void gemm_kernel(const uint8_t* __restrict__ qx,
                                                   const uint8_t* __restrict__ qw,
                                                   const float* __restrict__ sx,
                                                   const float* __restrict__ wscale,
                                                   const float* __restrict__ bias,
                                                   float* __restrict__ out) {
  __shared__ uint8_t As[BM * BK] __attribute__((aligned(16)));  // 16 KB
  __shared__ uint8_t Bs[BN * BK] __attribute__((aligned(16)));  // 16 KB
  const int t = threadIdx.x;
  const int m0 = blockIdx.y * BM;
  const int n0 = blockIdx.x * BN;
  const int lane = t & 63;
  const int wave = t >> 6;
  const int wr = wave >> 1;
  const int wc = wave & 1;
  const int lr = lane & 15;
  const int lq = lane >> 4;

  v4f acc[4][4] = {};

  // staging: call i covers rows i*32..i*32+31 (4 KB). thread t -> LDS i*4096+t*16;
  // global row = i*32 + (t>>3), logical chunk = (t&7) ^ (row&7).
  const int rA = t >> 3;  // 0..31
  const int csrc16 = (((t & 7) ^ (rA & 7)) << 4);
  const uint8_t* ga = qx + (size_t)(m0 + rA) * 4096 + csrc16;
  const uint8_t* gb = qw + (size_t)(n0 + rA) * 4096 + csrc16;
  const int ldst = t * 16;

  // fragment LDS offsets (k/tile-invariant swizzle: row&7 == lr&7)
  const int r7 = lr & 7;
  int aoff0[4], aoff1[4], boff0[4], boff1[4];
#pragma unroll
  for (int i = 0; i < 4; ++i) {
    const int rowa = (wr * 64 + i * 16 + lr) * 128;
    const int rowb = (wc * 64 + i * 16 + lr) * 128;
    aoff0[i] = rowa + (((2 * lq) ^ r7) << 4);
    aoff1[i] = rowa + (((2 * lq + 1) ^ r7) << 4);
    boff0[i] = rowb + (((2 * lq) ^ r7) << 4);
    boff1[i] = rowb + (((2 * lq + 1) ^ r7) << 4);
  }

  for (int k0 = 0; k0 < 4096; k0 += BK) {
    __syncthreads();
#pragma unroll
    for (int i = 0; i < 4; ++i) {
      gl_lds16(ga + k0 + (size_t)i * 32 * 4096, As + i * 4096 + ldst);
      gl_lds16(gb + k0 + (size_t)i * 32 * 4096, Bs + i * 4096 + ldst);
    }
    __syncthreads();

    union frag { v8i v; v4i h[2]; };
    frag a[4], b[4];
#pragma unroll
    for (int i = 0; i < 4; ++i) {
      a[i].h[0] = *(const v4i*)(As + aoff0[i]);
      a[i].h[1] = *(const v4i*)(As + aoff1[i]);
      b[i].h[0] = *(const v4i*)(Bs + boff0[i]);
      b[i].h[1] = *(const v4i*)(Bs + boff1[i]);
    }
#pragma unroll
    for (int mt = 0; mt < 4; ++mt)
#pragma unroll
      for (int nt = 0; nt < 4; ++nt)
        acc[mt][nt] = __builtin_amdgcn_mfma_scale_f32_16x16x128_f8f6f4(
            a[mt].v, b[nt].v, acc[mt][nt],
            0, 0,                      // cbsz=fp8(e4m3), blgp=fp8(e4m3)
            0, 0x7F7F7F7F,             // scale_a = 1.0 (E8M0 127)
            0, 0x7F7F7F7F);            // scale_b = 1.0
  }

  // epilogue: y = qy * sx[m] * ws[n] + bias[n]; C/D: col=lane&15, row=(lane>>4)*4+reg
#pragma unroll
  for (int mt = 0; mt < 4; ++mt) {
#pragma unroll
    for (int r = 0; r < 4; ++r) {
      const int m = m0 + wr * 64 + mt * 16 + lq * 4 + r;
      const float sm = sx[m];
#pragma unroll
      for (int nt = 0; nt < 4; ++nt) {
        const int n = n0 + wc * 64 + nt * 16 + lr;
        out[(size_t)m * 4096 + n] = acc[mt][nt][r] * sm * wscale[n] + bias[n];
      }
    }
  }
}

extern "C" void kernel_launch(void* const* d_in, const int* in_sizes, int n_in,
                              void* d_out, int out_size, void* d_ws, size_t ws_size,
                              hipStream_t stream) {
  const float* x = (const float*)d_in[0];
  const float* w = (const float*)d_in[1];
  const float* bias = (const float*)d_in[2];
  float* out = (float*)d_out;

  uint8_t* qx = (uint8_t*)d_ws;
  uint8_t* qw = qx + (size_t)8192 * 4096;
  float* wscale = (float*)(qw + (size_t)4096 * 4096);
  float* sxp = wscale + 4096;

  wquant_kernel<<<4096, 256, 0, stream>>>(w, qw, wscale);
  xquant_kernel<<<2048, 256, 0, stream>>>(x, qx, sxp);
  dim3 grid(4096 / BN, 8192 / BM);
  gemm_kernel<<<grid, 256, 0, stream>>>(qx, qw, sxp, wscale, bias, out);
}